// Round 4
// baseline (168.409 us; speedup 1.0000x reference)
//
#include <hip/hip_runtime.h>
#include <stdint.h>

// Dims fixed by reference: x [T=4,B=32,C=196,N=768] fp32; w1,w2,w3 [768][768] fp32.
#define T_STEPS 4
#define BC      6272            // B*C
#define NDIM    768
#define TBC     (T_STEPS*BC)    // 25088
#define BCN     (BC*NDIM)
#define FIX_CAP 65536
#define MARGIN  1e-4

typedef unsigned short u16;
typedef __attribute__((ext_vector_type(8))) __bf16 bf16x8;
typedef __attribute__((ext_vector_type(4))) float f32x4;

#define MFMA16(a,b,c) __builtin_amdgcn_mfma_f32_16x16x32_bf16((a),(b),(c),0,0,0)
#define SBAR()   __builtin_amdgcn_s_barrier()
#define SCHED0() __builtin_amdgcn_sched_barrier(0)

__device__ __forceinline__ u16 f2b(float f) {           // fp32 -> bf16 bits, RNE
    uint32_t u = __builtin_bit_cast(uint32_t, f);
    u += 0x7FFFu + ((u >> 16) & 1u);
    return (u16)(u >> 16);
}
__device__ __forceinline__ float b2f(u16 b) {
    uint32_t u = ((uint32_t)b) << 16;
    return __builtin_bit_cast(float, u);
}
__device__ __forceinline__ void gload16(const void* g, void* l) {
    __builtin_amdgcn_global_load_lds((const __attribute__((address_space(1))) void*)g,
                                     (__attribute__((address_space(3))) void*)l,
                                     16, 0, 0);
}

// ---------------------------------------------------------------------------
// s = lif(x) in fp64; spikes as bf16 {0,1} planes [t][bc][n].
// ---------------------------------------------------------------------------
__global__ __launch_bounds__(256) void lif_x_kernel(const float* __restrict__ x,
                                                    u16* __restrict__ s) {
    int idx = blockIdx.x * 256 + threadIdx.x;
    double v = 0.0;
    #pragma unroll
    for (int t = 0; t < T_STEPS; ++t) {
        v = 0.5 * v + (double)x[(size_t)t * BCN + idx];
        u16 sp = 0;
        if (v >= 1.0) { sp = 0x3F80u; v = 0.0; }   // bf16(1.0)
        s[(size_t)t * BCN + idx] = sp;
    }
}

// ---------------------------------------------------------------------------
// Weight prep: w1->bf16; w2->bf16 hi+lo; w3->bf16. Zero fixup counter.
// ---------------------------------------------------------------------------
__global__ __launch_bounds__(256) void prep_w_kernel(
    const float* __restrict__ w1, const float* __restrict__ w2,
    const float* __restrict__ w3,
    u16* __restrict__ w1b, u16* __restrict__ w2h,
    u16* __restrict__ w2l, u16* __restrict__ w3b,
    uint32_t* __restrict__ fix_cnt) {
    int i = blockIdx.x * 256 + threadIdx.x;
    if (i == 0) *fix_cnt = 0;
    w1b[i] = f2b(w1[i]);
    float w = w2[i];
    u16 h = f2b(w);
    w2h[i] = h;
    w2l[i] = f2b(w - b2f(h));
    w3b[i] = f2b(w3[i]);
}

// ---------------------------------------------------------------------------
// Kernel B: y1 = s@w1^T (bf16 MFMA), y2 = s@w2^T (split-bf16, ~1e-5 exact),
// fp64 LIF on y2 with near-threshold fixup list; z = y1*s3 (bf16).
// Counted-vmcnt pipeline: stage(next) || compute(cur); raw barriers; never
// drain vmcnt in the main loop (T3+T4), setprio around MFMA (T5).
// ---------------------------------------------------------------------------
__global__ __launch_bounds__(256) void y12_kernel(
    const u16* __restrict__ s,
    const u16* __restrict__ w1b, const u16* __restrict__ w2hb,
    const u16* __restrict__ w2lb,
    u16* __restrict__ z,
    uint32_t* __restrict__ fix_cnt,
    int2* __restrict__ fix_idx, float4* __restrict__ fix_y1)
{
    // per-buffer flat LDS (u16): As [0,8192) B1 [8192,12288) B2h [12288,16384)
    // B2l [16384,20480); 40KB x 2 = 80KB
    __shared__ u16 lds[2][20480];

    const int tid  = threadIdx.x;
    const int lane = tid & 63;
    const int wid  = tid >> 6;

    // XCD-chunked swizzle: nwg = 2352 = 8 * 294
    const int bid = blockIdx.x;
    const int swz = (bid & 7) * 294 + (bid >> 3);
    const int mb  = swz % (NDIM / 64);
    const int rb  = swz / (NDIM / 64);
    const int m0  = mb * 64;
    const int bc0 = rb * 32;

    // ---- staging: 40 chunks of 512 elems; 10 per wave ----
    const int lrow  = lane >> 3;
    const int scolE = ((((lane & 7) << 4) ^ (lrow << 4)) >> 1);
    const u16* gp[10];
    int lofs[10];
    #pragma unroll
    for (int c = 0; c < 10; ++c) {
        int chunk = wid * 10 + c;
        const u16* g;
        if (chunk < 16) {
            int grow = chunk * 8 + lrow;
            int t = grow >> 5, bcl = grow & 31;
            g = s + ((size_t)(t * BC + bc0 + bcl)) * NDIM + scolE;
        } else if (chunk < 24) {
            int grow = (chunk - 16) * 8 + lrow;
            g = w1b + ((size_t)(m0 + grow)) * NDIM + scolE;
        } else if (chunk < 32) {
            int grow = (chunk - 24) * 8 + lrow;
            g = w2hb + ((size_t)(m0 + grow)) * NDIM + scolE;
        } else {
            int grow = (chunk - 32) * 8 + lrow;
            g = w2lb + ((size_t)(m0 + grow)) * NDIM + scolE;
        }
        gp[c] = g;
        lofs[c] = chunk * 512;
    }

    const int swzb = (lane & 7) << 4;
    const int cb   = (lane >> 4) << 4;
    const int colE0 = ((cb     ) ^ swzb) >> 1;
    const int colE1 = ((cb | 64) ^ swzb) >> 1;
    int aoff[4][2];
    #pragma unroll
    for (int t = 0; t < 4; ++t)
        #pragma unroll
        for (int rt = 0; rt < 2; ++rt)
            aoff[t][rt] = (t * 32 + rt * 16 + (lane & 15)) * 64;
    const int boff = (wid * 16 + (lane & 15)) * 64;

    f32x4 acc1[4][2], acc2[4][2];
    #pragma unroll
    for (int t = 0; t < 4; ++t)
        #pragma unroll
        for (int rt = 0; rt < 2; ++rt) {
            acc1[t][rt] = (f32x4){0.f, 0.f, 0.f, 0.f};
            acc2[t][rt] = (f32x4){0.f, 0.f, 0.f, 0.f};
        }

    auto stage = [&](int buf) {
        #pragma unroll
        for (int c = 0; c < 10; ++c) {
            gload16(gp[c], &lds[buf][lofs[c]]);
            gp[c] += 64;
        }
    };
    auto compute = [&](int buf) {
        const u16* L = lds[buf];
        #pragma unroll
        for (int k2i = 0; k2i < 2; ++k2i) {
            const int ce = k2i ? colE1 : colE0;
            bf16x8 b1 = *(const bf16x8*)&L[ 8192 + boff + ce];
            bf16x8 bh = *(const bf16x8*)&L[12288 + boff + ce];
            bf16x8 bl = *(const bf16x8*)&L[16384 + boff + ce];
            #pragma unroll
            for (int t = 0; t < 4; ++t)
                #pragma unroll
                for (int rt = 0; rt < 2; ++rt) {
                    bf16x8 a = *(const bf16x8*)&L[aoff[t][rt] + ce];
                    acc1[t][rt] = MFMA16(a, b1, acc1[t][rt]);
                    acc2[t][rt] = MFMA16(a, bh, acc2[t][rt]);
                    acc2[t][rt] = MFMA16(a, bl, acc2[t][rt]);
                }
        }
    };

    // ---- counted-vmcnt pipeline over 12 K-tiles ----
    stage(0);                                   // t0 -> b0   (10 in flight)
    for (int it = 0; it < 11; ++it) {
        stage((it + 1) & 1);                    // t_{it+1}   (<=20 in flight)
        asm volatile("s_waitcnt vmcnt(10)" ::: "memory");   // t_it landed (mine)
        SBAR();                                 // t_it landed (all waves)
        SCHED0();
        __builtin_amdgcn_s_setprio(1);
        compute(it & 1);
        __builtin_amdgcn_s_setprio(0);
        SCHED0();
        SBAR();                                 // all reads of buf done -> overwrite ok
    }
    asm volatile("s_waitcnt vmcnt(0)" ::: "memory");        // t11 landed
    SBAR();
    SCHED0();
    __builtin_amdgcn_s_setprio(1);
    compute(1);
    __builtin_amdgcn_s_setprio(0);

    // ---- epilogue: fp64 LIF on y2, flag near-threshold, z = y1*s3 ----
    const int mg = m0 + wid * 16 + (lane & 15);
    #pragma unroll
    for (int rt = 0; rt < 2; ++rt) {
        #pragma unroll
        for (int r = 0; r < 4; ++r) {
            const int bcg = bc0 + rt * 16 + (lane >> 4) * 4 + r;
            double v = 0.0;
            bool flag = false;
            float zv[4];
            #pragma unroll
            for (int t = 0; t < 4; ++t) {
                v = 0.5 * v + (double)acc2[t][rt][r];
                double d = v - 1.0;
                flag |= (d < MARGIN && d > -MARGIN);
                if (v >= 1.0) { zv[t] = acc1[t][rt][r]; v = 0.0; }
                else          { zv[t] = 0.0f; }
            }
            if (flag) {
                uint32_t id = atomicAdd(fix_cnt, 1u);
                if (id < FIX_CAP) {
                    fix_idx[id] = make_int2(bcg, mg);
                    fix_y1[id]  = make_float4(acc1[0][rt][r], acc1[1][rt][r],
                                              acc1[2][rt][r], acc1[3][rt][r]);
                }
            }
            #pragma unroll
            for (int t = 0; t < 4; ++t)
                z[((size_t)(t * BC + bcg)) * NDIM + mg] = f2b(zv[t]);
        }
    }
}

// ---------------------------------------------------------------------------
// Exact fp64 recompute of flagged (bc,m) pairs; one wave per entry.
// ---------------------------------------------------------------------------
__global__ __launch_bounds__(256) void fixup_kernel(
    const u16* __restrict__ s, const float* __restrict__ w2,
    const int2* __restrict__ fix_idx, const float4* __restrict__ fix_y1,
    const uint32_t* __restrict__ fix_cnt, u16* __restrict__ z)
{
    const int lane = threadIdx.x & 63;
    const int wave = (blockIdx.x * 256 + threadIdx.x) >> 6;
    const int nw   = gridDim.x * 4;
    uint32_t n = *fix_cnt;
    if (n > FIX_CAP) n = FIX_CAP;

    for (uint32_t e = wave; e < n; e += nw) {
        const int bc = fix_idx[e].x, m = fix_idx[e].y;
        const float* w2row = w2 + (size_t)m * NDIM;
        double acc[4] = {0.0, 0.0, 0.0, 0.0};
        #pragma unroll
        for (int j = 0; j < NDIM / 64; ++j) {
            int nn = lane + j * 64;
            double wv = (double)w2row[nn];
            #pragma unroll
            for (int t = 0; t < 4; ++t)
                if (s[((size_t)(t * BC + bc)) * NDIM + nn]) acc[t] += wv;
        }
        #pragma unroll
        for (int o = 32; o > 0; o >>= 1)
            #pragma unroll
            for (int t = 0; t < 4; ++t) acc[t] += __shfl_xor(acc[t], o);
        if (lane == 0) {
            float4 y1 = fix_y1[e];
            float y1a[4] = {y1.x, y1.y, y1.z, y1.w};
            double v = 0.0;
            #pragma unroll
            for (int t = 0; t < 4; ++t) {
                v = 0.5 * v + acc[t];
                u16 zz = 0;
                if (v >= 1.0) { zz = f2b(y1a[t]); v = 0.0; }
                z[((size_t)(t * BC + bc)) * NDIM + m] = zz;
            }
        }
    }
}

// ---------------------------------------------------------------------------
// Kernel C: out[r][m] = sum_n z[r][n]*w3[m][n], bf16 MFMA, fp32 out.
// Same counted-vmcnt pipeline (4 loads/wave/tile -> vmcnt(4)).
// ---------------------------------------------------------------------------
__global__ __launch_bounds__(256) void out_kernel(
    const u16* __restrict__ z, const u16* __restrict__ w3b,
    float* __restrict__ out)
{
    __shared__ u16 lds[2][8192];   // Zs [0,4096) Ws [4096,8192); 16KB x 2

    const int tid  = threadIdx.x;
    const int lane = tid & 63;
    const int wid  = tid >> 6;

    // XCD-chunked swizzle: nwg = 4704 = 8 * 588
    const int bid = blockIdx.x;
    const int swz = (bid & 7) * 588 + (bid >> 3);
    const int mb  = swz % (NDIM / 64);
    const int rb  = swz / (NDIM / 64);
    const int m0  = mb * 64;
    const int r0  = rb * 64;

    const int lrow  = lane >> 3;
    const int scolE = ((((lane & 7) << 4) ^ (lrow << 4)) >> 1);
    const u16* gp[4];
    int lofs[4];
    #pragma unroll
    for (int c = 0; c < 4; ++c) {
        int chunk = wid * 4 + c;
        const u16* g;
        if (chunk < 8) {
            int grow = chunk * 8 + lrow;
            g = z + ((size_t)(r0 + grow)) * NDIM + scolE;
        } else {
            int grow = (chunk - 8) * 8 + lrow;
            g = w3b + ((size_t)(m0 + grow)) * NDIM + scolE;
        }
        gp[c] = g;
        lofs[c] = chunk * 512;
    }

    const int swzb = (lane & 7) << 4;
    const int cb   = (lane >> 4) << 4;
    const int colE0 = ((cb     ) ^ swzb) >> 1;
    const int colE1 = ((cb | 64) ^ swzb) >> 1;
    const int boff = (wid * 16 + (lane & 15)) * 64;

    f32x4 acc[4];
    #pragma unroll
    for (int rt = 0; rt < 4; ++rt) acc[rt] = (f32x4){0.f, 0.f, 0.f, 0.f};

    auto stage = [&](int buf) {
        #pragma unroll
        for (int c = 0; c < 4; ++c) {
            gload16(gp[c], &lds[buf][lofs[c]]);
            gp[c] += 64;
        }
    };
    auto compute = [&](int buf) {
        const u16* L = lds[buf];
        #pragma unroll
        for (int k2i = 0; k2i < 2; ++k2i) {
            const int ce = k2i ? colE1 : colE0;
            bf16x8 bw = *(const bf16x8*)&L[4096 + boff + ce];
            #pragma unroll
            for (int rt = 0; rt < 4; ++rt) {
                bf16x8 az = *(const bf16x8*)&L[(rt * 16 + (lane & 15)) * 64 + ce];
                acc[rt] = MFMA16(az, bw, acc[rt]);
            }
        }
    };

    stage(0);
    for (int it = 0; it < 11; ++it) {
        stage((it + 1) & 1);
        asm volatile("s_waitcnt vmcnt(4)" ::: "memory");
        SBAR();
        SCHED0();
        __builtin_amdgcn_s_setprio(1);
        compute(it & 1);
        __builtin_amdgcn_s_setprio(0);
        SCHED0();
        SBAR();
    }
    asm volatile("s_waitcnt vmcnt(0)" ::: "memory");
    SBAR();
    SCHED0();
    __builtin_amdgcn_s_setprio(1);
    compute(1);
    __builtin_amdgcn_s_setprio(0);

    #pragma unroll
    for (int rt = 0; rt < 4; ++rt)
        #pragma unroll
        for (int r = 0; r < 4; ++r)
            out[((size_t)(r0 + rt * 16 + (lane >> 4) * 4 + r)) * NDIM
                + m0 + wid * 16 + (lane & 15)] = acc[rt][r];
}

// ---------------------------------------------------------------------------
extern "C" void kernel_launch(void* const* d_in, const int* in_sizes, int n_in,
                              void* d_out, int out_size, void* d_ws, size_t ws_size,
                              hipStream_t stream) {
    const float* x  = (const float*)d_in[0];
    const float* w1 = (const float*)d_in[1];
    const float* w2 = (const float*)d_in[2];
    const float* w3 = (const float*)d_in[3];
    float* out = (float*)d_out;

    char* ws = (char*)d_ws;
    u16*      s       = (u16*)(ws);
    u16*      z       = (u16*)(ws + 38535168);
    u16*      w1b     = (u16*)(ws + 77070336);
    u16*      w2h     = (u16*)(ws + 78249984);
    u16*      w2l     = (u16*)(ws + 79429632);
    u16*      w3b     = (u16*)(ws + 80609280);
    uint32_t* fix_cnt = (uint32_t*)(ws + 81788928);
    int2*     fix_idx = (int2*)(ws + 81788992);
    float4*   fix_y1  = (float4*)(ws + 82313280);

    prep_w_kernel<<<(NDIM * NDIM) / 256, 256, 0, stream>>>(w1, w2, w3, w1b, w2h,
                                                           w2l, w3b, fix_cnt);
    lif_x_kernel<<<BCN / 256, 256, 0, stream>>>(x, s);
    y12_kernel<<<(BC / 32) * (NDIM / 64), 256, 0, stream>>>(s, w1b, w2h, w2l, z,
                                                            fix_cnt, fix_idx, fix_y1);
    fixup_kernel<<<128, 256, 0, stream>>>(s, w2, fix_idx, fix_y1, fix_cnt, z);
    out_kernel<<<(TBC / 64) * (NDIM / 64), 256, 0, stream>>>(z, w3b, out);
}

// Round 5
// 146.716 us; speedup vs baseline: 1.1479x; 1.1479x over previous
//
#include <hip/hip_runtime.h>
#include <stdint.h>

// Dims fixed by reference: x [T=4,B=32,C=196,N=768] fp32; w1,w2,w3 [768][768] fp32.
#define T_STEPS 4
#define BC      6272            // B*C
#define NDIM    768
#define TBC     (T_STEPS*BC)    // 25088
#define BCN     (BC*NDIM)
#define FIX_CAP 65536

typedef unsigned short u16;
typedef __attribute__((ext_vector_type(8))) __bf16 bf16x8;
typedef __attribute__((ext_vector_type(4))) float f32x4;
typedef __attribute__((ext_vector_type(4))) int   i32x4;

#define MFMA16(a,b,c)  __builtin_amdgcn_mfma_f32_16x16x32_bf16((a),(b),(c),0,0,0)
#define MFMAI8(a,b,c)  __builtin_amdgcn_mfma_i32_16x16x64_i8((a),(b),(c),0,0,0)

__device__ __forceinline__ u16 f2b(float f) {           // fp32 -> bf16 bits, RNE
    uint32_t u = __builtin_bit_cast(uint32_t, f);
    u += 0x7FFFu + ((u >> 16) & 1u);
    return (u16)(u >> 16);
}
__device__ __forceinline__ void gload16(const void* g, void* l) {
    __builtin_amdgcn_global_load_lds((const __attribute__((address_space(1))) void*)g,
                                     (__attribute__((address_space(3))) void*)l,
                                     16, 0, 0);
}

// ---------------------------------------------------------------------------
// s = lif(x) in fp64; spikes as i8 {0,1} planes [t][bc][n]. 4 n per thread.
// ---------------------------------------------------------------------------
__global__ __launch_bounds__(256) void lif_x_kernel(const float* __restrict__ x,
                                                    int8_t* __restrict__ s8) {
    int gid = blockIdx.x * 256 + threadIdx.x;          // [0, BCN/4)
    double v0 = 0, v1 = 0, v2 = 0, v3 = 0;
    #pragma unroll
    for (int t = 0; t < T_STEPS; ++t) {
        float4 xv = *(const float4*)&x[(size_t)t * BCN + (size_t)gid * 4];
        uint32_t pack = 0;
        v0 = 0.5 * v0 + (double)xv.x; if (v0 >= 1.0) { pack |= 1u;       v0 = 0.0; }
        v1 = 0.5 * v1 + (double)xv.y; if (v1 >= 1.0) { pack |= 1u << 8;  v1 = 0.0; }
        v2 = 0.5 * v2 + (double)xv.z; if (v2 >= 1.0) { pack |= 1u << 16; v2 = 0.0; }
        v3 = 0.5 * v3 + (double)xv.w; if (v3 >= 1.0) { pack |= 1u << 24; v3 = 0.0; }
        *(uint32_t*)&s8[(size_t)t * BCN + (size_t)gid * 4] = pack;
    }
}

// ---------------------------------------------------------------------------
// Per-(t,bc) spike counts (for the exact quantization-error margin).
// ---------------------------------------------------------------------------
__global__ __launch_bounds__(256) void cnt_kernel(const int8_t* __restrict__ s8,
                                                  u16* __restrict__ cnt) {
    int row  = blockIdx.x * 4 + (threadIdx.x >> 6);    // [0, TBC)
    int lane = threadIdx.x & 63;
    const uint32_t* p = (const uint32_t*)(s8 + (size_t)row * NDIM + lane * 12);
    uint32_t sum = 0;
    #pragma unroll
    for (int j = 0; j < 3; ++j) sum += (p[j] * 0x01010101u) >> 24;
    #pragma unroll
    for (int o = 32; o > 0; o >>= 1) sum += __shfl_xor(sum, o);
    if (lane == 0) cnt[row] = (u16)sum;
}

// ---------------------------------------------------------------------------
// Weight prep: w1 -> i8 (x512); w2 -> 2 i8 limbs of round(w2*65536);
// w3 -> bf16. Zero fixup counter.
// ---------------------------------------------------------------------------
__global__ __launch_bounds__(256) void prep_w_kernel(
    const float* __restrict__ w1, const float* __restrict__ w2,
    const float* __restrict__ w3,
    int8_t* __restrict__ w1q, int8_t* __restrict__ w2h,
    int8_t* __restrict__ w2l, u16* __restrict__ w3b,
    uint32_t* __restrict__ fix_cnt) {
    int i = blockIdx.x * 256 + threadIdx.x;
    if (i == 0) *fix_cnt = 0;
    int q1 = __float2int_rn(w1[i] * 512.0f);
    q1 = q1 > 127 ? 127 : (q1 < -127 ? -127 : q1);
    w1q[i] = (int8_t)q1;
    int q16 = __double2int_rn((double)w2[i] * 65536.0);
    int8_t lo = (int8_t)(q16 & 0xFF);
    int hi = (q16 - (int)lo) >> 8;                     // exact, |hi| <= ~49
    w2h[i] = (int8_t)hi;
    w2l[i] = lo;
    w3b[i] = f2b(w3[i]);
}

// ---------------------------------------------------------------------------
// Kernel B (all-i8): y1 = s@w1q^T, y2 = s@(w2h,w2l)^T with exact i32 accum.
// fp64 LIF on y2_q with per-row hard error margin -> fixup list; z = y1*s3.
// Block: bc-tile 32 (A rows 128 = 4t x 32), m-tile 64, 4 waves (16-m each).
// K-step 128 (two K=64 MFMA subtiles per row). LDS rows 128B, XOR-swizzled
// (slot ^= row&7) via pre-swizzled gload source; 40KB/buf x2 = 80KB.
// ---------------------------------------------------------------------------
__global__ __launch_bounds__(256) void y12_kernel(
    const int8_t* __restrict__ s8,
    const int8_t* __restrict__ w1q, const int8_t* __restrict__ w2hb,
    const int8_t* __restrict__ w2lb,
    const u16* __restrict__ cnt,
    u16* __restrict__ z,
    uint32_t* __restrict__ fix_cnt,
    int2* __restrict__ fix_idx, float4* __restrict__ fix_y1)
{
    // per-buffer: As [0,16384) 128x128B; B1 [16384,24576); B2h [24576,32768);
    // B2l [32768,40960)
    __shared__ int8_t lds[2][40960];

    const int tid  = threadIdx.x;
    const int lane = tid & 63;
    const int wid  = tid >> 6;

    // XCD-chunked swizzle: nwg = 2352 = 8 * 294
    const int bid = blockIdx.x;
    const int swz = (bid & 7) * 294 + (bid >> 3);
    const int mb  = swz % (NDIM / 64);
    const int rb  = swz / (NDIM / 64);
    const int m0  = mb * 64;
    const int bc0 = rb * 32;

    // ---- staging: 40 chunks of 1KB (8 rows x 128B); 10 per wave ----
    const int srow  = lane >> 3;                       // row in 8-row chunk
    const int scolB = ((lane & 7) << 4) ^ (srow << 4); // pre-swizzled src byte col
    const int8_t* gp[10];
    int lofs[10];
    #pragma unroll
    for (int c = 0; c < 10; ++c) {
        int chunk = wid * 10 + c;
        const int8_t* g;
        int l;
        if (chunk < 16) {                              // A: 128 rows = t*32+bcl
            int gr = chunk * 8 + srow;
            int t = gr >> 5, bcl = gr & 31;
            g = s8 + ((size_t)(t * BC + bc0 + bcl)) * NDIM + scolB;
            l = chunk * 1024;
        } else if (chunk < 24) {
            int mr = (chunk - 16) * 8 + srow;
            g = w1q + ((size_t)(m0 + mr)) * NDIM + scolB;
            l = 16384 + (chunk - 16) * 1024;
        } else if (chunk < 32) {
            int mr = (chunk - 24) * 8 + srow;
            g = w2hb + ((size_t)(m0 + mr)) * NDIM + scolB;
            l = 24576 + (chunk - 24) * 1024;
        } else {
            int mr = (chunk - 32) * 8 + srow;
            g = w2lb + ((size_t)(m0 + mr)) * NDIM + scolB;
            l = 32768 + (chunk - 32) * 1024;
        }
        gp[c] = g;
        lofs[c] = l;
    }

    // ---- fragment read offsets ----
    const int key = lane & 7;
    const int g4  = lane >> 4;                         // k-group 0..3
    int slotA[2];
    slotA[0] = ((g4     ^ key) << 4);                  // ks=0: slots 0..3
    slotA[1] = (((4|g4) ^ key) << 4);                  // ks=1: slots 4..7
    int abase[8];
    #pragma unroll
    for (int t = 0; t < 4; ++t)
        #pragma unroll
        for (int rt = 0; rt < 2; ++rt)
            abase[t * 2 + rt] = (t * 32 + rt * 16 + (lane & 15)) * 128;
    const int bbase = (wid * 16 + (lane & 15)) * 128;

    i32x4 acc1[4][2], acch[4][2], accl[4][2];
    #pragma unroll
    for (int t = 0; t < 4; ++t)
        #pragma unroll
        for (int rt = 0; rt < 2; ++rt) {
            acc1[t][rt] = (i32x4){0, 0, 0, 0};
            acch[t][rt] = (i32x4){0, 0, 0, 0};
            accl[t][rt] = (i32x4){0, 0, 0, 0};
        }

    auto stage = [&](int buf) {
        #pragma unroll
        for (int c = 0; c < 10; ++c) {
            gload16(gp[c], &lds[buf][lofs[c]]);
            gp[c] += 128;
        }
    };
    auto compute = [&](int buf) {
        const int8_t* L = lds[buf];
        #pragma unroll
        for (int ks = 0; ks < 2; ++ks) {
            const int sl = slotA[ks];
            i32x4 b1 = *(const i32x4*)&L[16384 + bbase + sl];
            i32x4 bh = *(const i32x4*)&L[24576 + bbase + sl];
            i32x4 bl = *(const i32x4*)&L[32768 + bbase + sl];
            #pragma unroll
            for (int t = 0; t < 4; ++t)
                #pragma unroll
                for (int rt = 0; rt < 2; ++rt) {
                    i32x4 a = *(const i32x4*)&L[abase[t * 2 + rt] + sl];
                    acc1[t][rt] = MFMAI8(a, b1, acc1[t][rt]);
                    acch[t][rt] = MFMAI8(a, bh, acch[t][rt]);
                    accl[t][rt] = MFMAI8(a, bl, accl[t][rt]);
                }
        }
    };

    // ---- 2-phase dbuf over 6 K-128 tiles ----
    stage(0);
    __syncthreads();
    #pragma unroll
    for (int it = 0; it < 5; ++it) {
        stage((it + 1) & 1);
        compute(it & 1);
        __syncthreads();
    }
    compute(1);

    // ---- epilogue: exact y2_q, fp64 LIF with hard margin, z = y1*s3 ----
    const int mg = m0 + wid * 16 + (lane & 15);
    #pragma unroll
    for (int rt = 0; rt < 2; ++rt) {
        #pragma unroll
        for (int r = 0; r < 4; ++r) {
            const int bcg = bc0 + rt * 16 + (lane >> 4) * 4 + r;
            double v = 0.0, e = 0.0;
            bool flag = false;
            float zv[4], y1v[4];
            #pragma unroll
            for (int t = 0; t < 4; ++t) {
                float y1 = (float)acc1[t][rt][r] * (1.0f / 512.0f);
                y1v[t] = y1;
                double y2 = (double)(acch[t][rt][r] * 256 + accl[t][rt][r])
                            * (1.0 / 65536.0);
                v = 0.5 * v + y2;
                e = 0.5 * e + 7.62939453125e-6 * (double)cnt[t * BC + bcg] + 1e-9;
                double d = v - 1.0;
                flag |= (d <= e && d >= -e);
                if (v >= 1.0) { zv[t] = y1; v = 0.0; }
                else          { zv[t] = 0.0f; }
            }
            if (flag) {
                uint32_t id = atomicAdd(fix_cnt, 1u);
                if (id < FIX_CAP) {
                    fix_idx[id] = make_int2(bcg, mg);
                    fix_y1[id]  = make_float4(y1v[0], y1v[1], y1v[2], y1v[3]);
                }
            }
            #pragma unroll
            for (int t = 0; t < 4; ++t)
                z[((size_t)(t * BC + bcg)) * NDIM + mg] = f2b(zv[t]);
        }
    }
}

// ---------------------------------------------------------------------------
// Exact fp64 recompute of flagged (bc,m) pairs; one wave per entry.
// ---------------------------------------------------------------------------
__global__ __launch_bounds__(256) void fixup_kernel(
    const int8_t* __restrict__ s8, const float* __restrict__ w2,
    const int2* __restrict__ fix_idx, const float4* __restrict__ fix_y1,
    const uint32_t* __restrict__ fix_cnt, u16* __restrict__ z)
{
    const int lane = threadIdx.x & 63;
    const int wave = (blockIdx.x * 256 + threadIdx.x) >> 6;
    const int nw   = gridDim.x * 4;
    uint32_t n = *fix_cnt;
    if (n > FIX_CAP) n = FIX_CAP;

    for (uint32_t e = wave; e < n; e += nw) {
        const int bc = fix_idx[e].x, m = fix_idx[e].y;
        const float* w2row = w2 + (size_t)m * NDIM;
        double acc[4] = {0.0, 0.0, 0.0, 0.0};
        #pragma unroll
        for (int j = 0; j < NDIM / 64; ++j) {
            int nn = lane + j * 64;
            double wv = (double)w2row[nn];
            #pragma unroll
            for (int t = 0; t < 4; ++t)
                if (s8[((size_t)(t * BC + bc)) * NDIM + nn]) acc[t] += wv;
        }
        #pragma unroll
        for (int o = 32; o > 0; o >>= 1)
            #pragma unroll
            for (int t = 0; t < 4; ++t) acc[t] += __shfl_xor(acc[t], o);
        if (lane == 0) {
            float4 y1 = fix_y1[e];
            float y1a[4] = {y1.x, y1.y, y1.z, y1.w};
            double v = 0.0;
            #pragma unroll
            for (int t = 0; t < 4; ++t) {
                v = 0.5 * v + acc[t];
                u16 zz = 0;
                if (v >= 1.0) { zz = f2b(y1a[t]); v = 0.0; }
                z[((size_t)(t * BC + bc)) * NDIM + m] = zz;
            }
        }
    }
}

// ---------------------------------------------------------------------------
// Kernel C: out[r][m] = sum_n z[r][n]*w3[m][n], bf16 MFMA, fp32 out.
// 64x64 tile, 2-phase dbuf (round-3 structure).
// ---------------------------------------------------------------------------
__global__ __launch_bounds__(256) void out_kernel(
    const u16* __restrict__ z, const u16* __restrict__ w3b,
    float* __restrict__ out)
{
    __shared__ u16 lds[2][8192];   // Zs [0,4096) Ws [4096,8192)

    const int tid  = threadIdx.x;
    const int lane = tid & 63;
    const int wid  = tid >> 6;

    const int bid = blockIdx.x;                        // nwg 4704 = 8*588
    const int swz = (bid & 7) * 588 + (bid >> 3);
    const int mb  = swz % (NDIM / 64);
    const int rb  = swz / (NDIM / 64);
    const int m0  = mb * 64;
    const int r0  = rb * 64;

    const int lrow  = lane >> 3;
    const int scolE = ((((lane & 7) << 4) ^ (lrow << 4)) >> 1);
    const u16* gp[4];
    int lofs[4];
    #pragma unroll
    for (int c = 0; c < 4; ++c) {
        int chunk = wid * 4 + c;
        const u16* g;
        if (chunk < 8) {
            int grow = chunk * 8 + lrow;
            g = z + ((size_t)(r0 + grow)) * NDIM + scolE;
        } else {
            int grow = (chunk - 8) * 8 + lrow;
            g = w3b + ((size_t)(m0 + grow)) * NDIM + scolE;
        }
        gp[c] = g;
        lofs[c] = chunk * 512;
    }

    const int swzb = (lane & 7) << 4;
    const int cb   = (lane >> 4) << 4;
    const int colE0 = ((cb     ) ^ swzb) >> 1;
    const int colE1 = ((cb | 64) ^ swzb) >> 1;
    const int boff = (wid * 16 + (lane & 15)) * 64;

    f32x4 acc[4];
    #pragma unroll
    for (int rt = 0; rt < 4; ++rt) acc[rt] = (f32x4){0.f, 0.f, 0.f, 0.f};

    auto stage = [&](int buf) {
        #pragma unroll
        for (int c = 0; c < 4; ++c) {
            gload16(gp[c], &lds[buf][lofs[c]]);
            gp[c] += 64;
        }
    };
    auto compute = [&](int buf) {
        const u16* L = lds[buf];
        #pragma unroll
        for (int k2i = 0; k2i < 2; ++k2i) {
            const int ce = k2i ? colE1 : colE0;
            bf16x8 bw = *(const bf16x8*)&L[4096 + boff + ce];
            #pragma unroll
            for (int rt = 0; rt < 4; ++rt) {
                bf16x8 az = *(const bf16x8*)&L[(rt * 16 + (lane & 15)) * 64 + ce];
                acc[rt] = MFMA16(az, bw, acc[rt]);
            }
        }
    };

    stage(0);
    __syncthreads();
    for (int it = 0; it < 11; ++it) {
        stage((it + 1) & 1);
        compute(it & 1);
        __syncthreads();
    }
    compute(1);

    #pragma unroll
    for (int rt = 0; rt < 4; ++rt)
        #pragma unroll
        for (int r = 0; r < 4; ++r)
            out[((size_t)(r0 + rt * 16 + (lane >> 4) * 4 + r)) * NDIM
                + m0 + wid * 16 + (lane & 15)] = acc[rt][r];
}

// ---------------------------------------------------------------------------
extern "C" void kernel_launch(void* const* d_in, const int* in_sizes, int n_in,
                              void* d_out, int out_size, void* d_ws, size_t ws_size,
                              hipStream_t stream) {
    const float* x  = (const float*)d_in[0];
    const float* w1 = (const float*)d_in[1];
    const float* w2 = (const float*)d_in[2];
    const float* w3 = (const float*)d_in[3];
    float* out = (float*)d_out;

    // workspace layout (bytes)
    char* ws = (char*)d_ws;
    int8_t*   s8      = (int8_t*)(ws);                    // 19,267,584
    u16*      z       = (u16*)(ws + 19267584);            // 38,535,168
    int8_t*   w1q     = (int8_t*)(ws + 57802752);         //    589,824
    int8_t*   w2h     = (int8_t*)(ws + 58392576);         //    589,824
    int8_t*   w2l     = (int8_t*)(ws + 58982400);         //    589,824
    u16*      w3b     = (u16*)(ws + 59572224);            //  1,179,648
    u16*      cnt     = (u16*)(ws + 60751872);            //     50,176
    uint32_t* fix_cnt = (uint32_t*)(ws + 60802048);
    int2*     fix_idx = (int2*)(ws + 60802112);           //    524,288
    float4*   fix_y1  = (float4*)(ws + 61326400);         //  1,048,576

    prep_w_kernel<<<(NDIM * NDIM) / 256, 256, 0, stream>>>(w1, w2, w3, w1q, w2h,
                                                           w2l, w3b, fix_cnt);
    lif_x_kernel<<<BCN / 4 / 256, 256, 0, stream>>>(x, s8);
    cnt_kernel<<<TBC / 4, 256, 0, stream>>>(s8, cnt);
    y12_kernel<<<(BC / 32) * (NDIM / 64), 256, 0, stream>>>(s8, w1q, w2h, w2l,
                                                            cnt, z, fix_cnt,
                                                            fix_idx, fix_y1);
    fixup_kernel<<<128, 256, 0, stream>>>(s8, w2, fix_idx, fix_y1, fix_cnt, z);
    out_kernel<<<(TBC / 64) * (NDIM / 64), 256, 0, stream>>>(z, w3b, out);
}